// Round 5
// baseline (427.971 us; speedup 1.0000x reference)
//
#include <hip/hip_runtime.h>

typedef unsigned short u16;
typedef __bf16 bf16x8 __attribute__((ext_vector_type(8)));
typedef float f32x4 __attribute__((ext_vector_type(4)));

__device__ __forceinline__ u16 f2bf(float f) {
  unsigned int u = __builtin_bit_cast(unsigned int, f);
  u += 0x7fffu + ((u >> 16) & 1u);
  return (u16)(u >> 16);
}

// async global->LDS, 16B per lane. LDS dest is wave-uniform base + lane*16 (HW).
__device__ __forceinline__ void gload_lds16(const u16* g, u16* l) {
  __builtin_amdgcn_global_load_lds((const __attribute__((address_space(1))) unsigned int*)g,
                                   (__attribute__((address_space(3))) unsigned int*)l,
                                   16, 0, 0);
}

// Branchless gelu with A&S 7.1.26 erf approx (|err|<=1.5e-7 abs, << bf16 rounding).
__device__ __forceinline__ float gelu_erf(float v) {
  const float z = v * 0.70710678118654752f;
  const float az = fabsf(z);
  const float t = __builtin_amdgcn_rcpf(1.0f + 0.3275911f * az);
  const float p = t * (0.254829592f +
                  t * (-0.284496736f +
                  t * (1.421413741f +
                  t * (-1.453152027f + t * 1.061405429f))));
  const float e = __expf(-az * az);
  float er = 1.0f - p * e;
  er = (z < 0.f) ? -er : er;
  return 0.5f * v * (1.0f + er);
}

// ===== Fragment-major (FM) layout for 16x16x32 bf16 MFMA operands =====
// chunk (ri=r>>4, ki=k>>5) is 64 lanes x 16B, contiguous 1KB:
//   lane = (r&15) | (((k>>3)&3)<<4),  byte = (k&7)*2
//   u16 addr(r,k) = ((ri*KC + ki)*512) + lane*8 + (k&7)      [KC = K/32]

// ---------------- WT[j][c] = sum_s rmsw[s*1024+c] * Wdyn[(s*1024+c)*24 + j] ------------
__global__ __launch_bounds__(256) void weff_kernel(const float* __restrict__ rmsw,
                                                   const float* __restrict__ Wdyn,
                                                   float* __restrict__ WT) {
  int idx = blockIdx.x * 256 + threadIdx.x;  // 24576 threads
  int j = idx >> 10, c = idx & 1023;
  float s = 0.f;
#pragma unroll
  for (int st = 0; st < 4; ++st) {
    int r = st * 1024 + c;
    s += rmsw[r] * Wdyn[(long)r * 24 + j];
  }
  WT[idx] = s;
}

// ---------------- pack all 3 weights (K x N fp32) -> FM bf16 of B^T in ONE dispatch ----
__global__ __launch_bounds__(256) void pack_all(const float* __restrict__ W1,
                                                const float* __restrict__ W2,
                                                const float* __restrict__ WO,
                                                u16* __restrict__ F1,
                                                u16* __restrict__ F2,
                                                u16* __restrict__ FO) {
  const int blk = blockIdx.x;
  const int sel = blk >> 11;  // 0,1,2 (2048 blocks each)
  const float* W;
  u16* FMB;
  int lgN, KC;
  if (sel == 0)      { W = W1; FMB = F1; lgN = 12; KC = 32; }
  else if (sel == 1) { W = W2; FMB = F2; lgN = 10; KC = 128; }
  else               { W = WO; FMB = FO; lgN = 10; KC = 128; }
  const long gid = (long)(blk & 2047) * 256 + threadIdx.x;  // N*K/8 threads
  const int N = 1 << lgN;
  const int n = (int)(gid & (N - 1));
  const int k0 = (int)(gid >> lgN) * 8;
  unsigned int p[4];
#pragma unroll
  for (int d = 0; d < 4; ++d) {
    const float lo = W[(long)(k0 + 2 * d) * N + n];
    const float hi = W[(long)(k0 + 2 * d + 1) * N + n];
    p[d] = (unsigned)f2bf(lo) | ((unsigned)f2bf(hi) << 16);
  }
  const long ad = ((long)(n >> 4) * KC + (k0 >> 5)) * 512 +
                  ((n & 15) + (((k0 >> 3) & 3) << 4)) * 8;
  *(uint4*)(FMB + ad) = make_uint4(p[0], p[1], p[2], p[3]);
}

// ---------------- per-token prep v3: 16 tokens/block, WT staged in LDS -----------------
// v2 had every (tt,cc) thread re-read all 24 WT rows from L2: 16x replication = 786MB of
// L2 traffic. v3 stages WT once per block (96KB LDS), reads via LDS broadcast, then
// reuses the same LDS as the reduction buffer after a barrier.
__global__ __launch_bounds__(512) void prep_tokens(
    const float* __restrict__ x, const float* __restrict__ WT,
    const float* __restrict__ bias_pre, const float* __restrict__ bias_post,
    const float* __restrict__ bias_res, const float* __restrict__ a_pre,
    const float* __restrict__ a_post, const float* __restrict__ a_res,
    u16* __restrict__ preA, float* __restrict__ scal) {
  const int tid = threadIdx.x;
  const int b = blockIdx.x;          // 512 blocks, 16 tokens each
  const long t0 = (long)b * 16;

  __shared__ float smem[24 * 1024];  // 96KB: WT staging, then red[32][16][26]
  __shared__ float tot2[16][26];
  __shared__ float spre[16];

  // ---- phase 0: WT -> LDS (coalesced float4) ----
#pragma unroll
  for (int q = 0; q < 12; ++q) {
    const int o = (q * 512 + tid) * 4;
    *(float4*)(smem + o) = *(const float4*)(WT + o);
  }
  __syncthreads();

  // ---- phase 1: partial dots (thread = (tt = tid&15, cc = tid>>4), 32 c's each) ----
  float part[25];
  {
    const int tt = tid & 15;
    const int cc = tid >> 4;  // 0..31
    const float* xp = x + (t0 + tt) * 1024 + cc * 32;
#pragma unroll
    for (int j = 0; j < 25; ++j) part[j] = 0.f;
#pragma unroll
    for (int g = 0; g < 8; ++g) {
      const float4 xv = *(const float4*)(xp + g * 4);
      part[24] += xv.x * xv.x + xv.y * xv.y + xv.z * xv.z + xv.w * xv.w;
#pragma unroll
      for (int j = 0; j < 24; ++j) {
        const float4 wv = *(const float4*)(smem + j * 1024 + cc * 32 + g * 4);
        part[j] += xv.x * wv.x + xv.y * wv.y + xv.z * wv.z + xv.w * wv.w;
      }
    }
  }
  __syncthreads();  // all WT reads done -> smem reusable as red
  float (*red)[16][26] = (float(*)[16][26])smem;  // [cc][tt][j]
  {
    const int tt = tid & 15;
    const int cc = tid >> 4;
#pragma unroll
    for (int j = 0; j < 25; ++j) red[cc][tt][j] = part[j];
  }
  __syncthreads();

  // ---- phase 2a: reduce over cc (thread = (tt = tid>>5, j = tid&31)) ----
  {
    const int tt = tid >> 5;
    const int j = tid & 31;
    if (j < 25) {
      float s = 0.f;
#pragma unroll
      for (int cc = 0; cc < 32; ++cc) s += red[cc][tt][j];
      tot2[tt][j] = s;
    }
  }
  __syncthreads();

  // ---- phase 2b: gates + sinkhorn (tid<256: thread = (tt = tid>>4, m = tid&15)) ----
  if (tid < 256) {
    const int tt = tid >> 4;
    const int m = tid & 15;
    const long t = t0 + tt;
    const float rms = sqrtf(tot2[tt][24] * (1.0f / 1024.0f) + 1e-8f);
    const float rinv = 1.0f / rms;

    if (m == 0) {
      const float ap = a_pre[0];
      float s_pre = 0.f;
#pragma unroll
      for (int i = 0; i < 4; ++i)
        s_pre += 1.f / (1.f + expf(-(ap * tot2[tt][i] * rinv + bias_pre[i])));
      spre[tt] = s_pre;
    }
    if (m < 4) {
      const float apo = a_post[0];
      float hp = 2.f / (1.f + expf(-(apo * tot2[tt][4 + m] * rinv + bias_post[m])));
      scal[t * 8 + 4 + m] = hp;  // H_post
    }
    const float ar = a_res[0];
    float Mv = expf(ar * tot2[tt][8 + m] * rinv + bias_res[m]);
#pragma unroll
    for (int it = 0; it < 20; ++it) {
      float cs = Mv + __shfl_xor(Mv, 4);
      cs += __shfl_xor(cs, 8);
      Mv = Mv / (cs + 1e-8f);  // col normalize (axis=-2)
      float rs = Mv + __shfl_xor(Mv, 1);
      rs += __shfl_xor(rs, 2);
      Mv = Mv / (rs + 1e-8f);  // row normalize (axis=-1)
    }
    float rs = Mv + __shfl_xor(Mv, 1);
    rs += __shfl_xor(rs, 2);
    if ((m & 3) == 0) scal[t * 8 + (m >> 2)] = rs;  // r_i
  }
  __syncthreads();

  // ---- phase 3: preA as complete FM chunks, coalesced uint4 stores ----
  {
    const int w = tid >> 6;
    const int lane = tid & 63;
    const int tl = lane & 15;
    const int co = (lane >> 4) * 8;
    const float sp = spre[tl];
#pragma unroll
    for (int p = 0; p < 4; ++p) {
      const int ki = p * 8 + w;
      const float* xr = x + (t0 + tl) * 1024 + ki * 32 + co;
      const float4 xa = *(const float4*)(xr);
      const float4 xb = *(const float4*)(xr + 4);
      unsigned q0 = (unsigned)f2bf(sp * xa.x) | ((unsigned)f2bf(sp * xa.y) << 16);
      unsigned q1 = (unsigned)f2bf(sp * xa.z) | ((unsigned)f2bf(sp * xa.w) << 16);
      unsigned q2 = (unsigned)f2bf(sp * xb.x) | ((unsigned)f2bf(sp * xb.y) << 16);
      unsigned q3 = (unsigned)f2bf(sp * xb.z) | ((unsigned)f2bf(sp * xb.w) << 16);
      *(uint4*)(preA + ((long)b * 32 + ki) * 512 + lane * 8) = make_uint4(q0, q1, q2, q3);
    }
  }
}

// ======== Deep-pipelined FM GEMM (T3+T4 counted-vmcnt + T5 setprio), XCD-swizzled ======
// Tile: 256 x (NT*16) with 8 waves, BK=32 (one FM k-chunk per step).
//   NT=8 (256x128): waves 4x2, wave tile 64x64 (AI=4), SC=3 chunks staged/wave/step
//   (NT=16 regressed in R4: its per-XCD B footprint needed ~4.5 TB/s of L2-miss BW)
// LDS: 4 staging buffers (depth-3 pipeline), CH=16+NT chunks of 1KB each.
// Ledger (per wave, SC loads/stage): iter kt issues stage kt+3; at iter end wait
// vmcnt(2*SC) -> stages {kt+2,kt+3} in flight, kt+1 complete; raw s_barrier.
// Tail: kt==KC-3 -> vmcnt(SC); kt>=KC-2 -> vmcnt(0). Never full drain mid-loop.
// SWZ=0: by = c*4 + s>>LGGX, bx = s&(GX-1)      (1 pass of 256 blocks)
// SWZ=1: 1024 blocks, 4 passes; per XCD-pass a 4(by) x 8(bx) sub-grid -> A 2MB + B 2MB
//        = 4MB, exactly L2-resident per XCD-pass.
template <int EPI, int NT, int SWZ, int LGGX>
__global__ __launch_bounds__(512, 2) void gemm_fm2(const u16* __restrict__ A,
                                                   const u16* __restrict__ B,
                                                   const int KCtot, const int KCout,
                                                   const float* __restrict__ bias,
                                                   const float* __restrict__ X,
                                                   const float* __restrict__ scal,
                                                   void* __restrict__ dstv) {
  constexpr int CH = 16 + NT;     // chunks per K-step (A rows 0..15, B rows 16..CH-1)
  constexpr int SC = CH / 8;      // chunks staged per wave per K-step
  constexpr int AI = (NT == 16) ? 8 : 4;
  const int tid = threadIdx.x;
  const int lane = tid & 63;
  const int wave = tid >> 6;
  const int wm = (NT == 16) ? (wave >> 2) : (wave >> 1);
  const int wn = (NT == 16) ? (wave & 3) : (wave & 1);
  const int b = blockIdx.x;
  int bx, by;
  if constexpr (SWZ == 1) {
    const int c = b & 7, u = b >> 3;   // c = XCD (round-robin dispatch)
    const int p = u >> 5, v = u & 31;  // pass 0..3, intra-XCD-pass 0..31
    by = (p * 2 + (c >> 2)) * 4 + (v >> 3);  // 0..31
    bx = (c & 3) * 8 + (v & 7);              // 0..31
  } else {
    const int c = b & 7, s = b >> 3;
    bx = s & ((1 << LGGX) - 1);
    by = c * 4 + (s >> LGGX);
  }

  __shared__ u16 lds[4][CH][512];
  u16* const l0 = (u16*)lds;

  // per-wave staging sources: chunk t = wave*SC + l
  const u16* gb[4];
#pragma unroll
  for (int l = 0; l < SC; ++l) {
    const int t = wave * SC + l;
    gb[l] = (t < 16) ? (A + ((long)(by * 16 + t) * KCtot) * 512 + lane * 8)
                     : (B + ((long)(bx * NT + (t - 16)) * KCtot) * 512 + lane * 8);
  }

#define STG(kt)                                                              \
  {                                                                          \
    u16* cb_ = l0 + (((kt) & 3) * CH + wave * SC) * 512;                     \
    const long ko_ = (long)(kt)*512;                                         \
    _Pragma("unroll") for (int l_ = 0; l_ < SC; ++l_)                        \
        gload_lds16(gb[l_] + ko_, cb_ + l_ * 512);                           \
  }

  f32x4 acc[AI][4] = {};

  // prologue: stage 0,1,2; ensure stage 0 landed (leave 1,2 in flight)
  STG(0); STG(1); STG(2);
  if constexpr (SC == 4) asm volatile("s_waitcnt vmcnt(8)" ::: "memory");
  else                   asm volatile("s_waitcnt vmcnt(6)" ::: "memory");
  __builtin_amdgcn_s_barrier();

  for (int kt = 0; kt < KCtot; ++kt) {
    if (kt + 3 < KCtot) STG(kt + 3);
    const u16* cb = l0 + (kt & 3) * (CH * 512);
    bf16x8 af[AI], bf[4];
#pragma unroll
    for (int i = 0; i < AI; ++i)
      af[i] = *(const bf16x8*)(cb + (wm * AI + i) * 512 + lane * 8);
#pragma unroll
    for (int j = 0; j < 4; ++j)
      bf[j] = *(const bf16x8*)(cb + (16 + wn * 4 + j) * 512 + lane * 8);
    // force LDS reads complete before this wave passes the barrier (WAR vs next stage)
    asm volatile("s_waitcnt lgkmcnt(0)" ::: "memory");
    __builtin_amdgcn_sched_barrier(0);
    __builtin_amdgcn_s_setprio(1);
#pragma unroll
    for (int i = 0; i < AI; ++i)
#pragma unroll
      for (int j = 0; j < 4; ++j)
        acc[i][j] = __builtin_amdgcn_mfma_f32_16x16x32_bf16(af[i], bf[j], acc[i][j], 0, 0, 0);
    __builtin_amdgcn_s_setprio(0);
    // counted drain: stage kt+1 must be complete; keep kt+2, kt+3 in flight
    if (kt + 4 <= KCtot) {
      if constexpr (SC == 4) asm volatile("s_waitcnt vmcnt(8)" ::: "memory");
      else                   asm volatile("s_waitcnt vmcnt(6)" ::: "memory");
    } else if (kt + 3 == KCtot) {
      if constexpr (SC == 4) asm volatile("s_waitcnt vmcnt(4)" ::: "memory");
      else                   asm volatile("s_waitcnt vmcnt(3)" ::: "memory");
    } else {
      asm volatile("s_waitcnt vmcnt(0)" ::: "memory");
    }
    __builtin_amdgcn_s_barrier();
  }
#undef STG

  // ---- Epilogue. C/D layout: col = lane&15, row = (lane>>4)*4 + reg [m89/m91] ----
  // LDS staging dead; bounce regions are WAVE-PRIVATE (in-wave ds ordering via lgkmcnt).
  if constexpr (EPI == 0) {
    u16* dst = (u16*)dstv;               // FM dst (h), KCout chunks per row-group
    u16* ep = l0 + wave * (2 * AI * 512);  // 2*AI KB per wave
#pragma unroll
    for (int i = 0; i < AI; ++i)
#pragma unroll
      for (int j = 0; j < 4; ++j) {
        const int col = bx * (NT * 16) + wn * 64 + j * 16 + (lane & 15);
        const float bcol = bias[col];
#pragma unroll
        for (int r = 0; r < 4; ++r) {
          const float g = gelu_erf(acc[i][j][r] + bcol);
          const int lp = ((lane >> 4) * 4 + r) | ((((j & 1) << 1) | ((lane & 15) >> 3)) << 4);
          ep[(i * 2 + (j >> 1)) * 512 + lp * 8 + (lane & 7)] = f2bf(g);
        }
      }
#pragma unroll
    for (int ch = 0; ch < 2 * AI; ++ch) {
      const int i = ch >> 1, jc = ch & 1;
      const long row16 = by * 16 + wm * AI + i;
      const long col32 = bx * (NT / 2) + wn * 2 + jc;
      *(uint4*)(dst + (row16 * KCout + col32) * 512 + lane * 8) =
          *(const uint4*)(ep + ch * 512 + lane * 8);
    }
  } else if constexpr (EPI == 1) {
    u16* dst = (u16*)dstv;          // merged FM, 128 chunks/rowgroup (k = ss*1024+col)
    u16* ep = l0 + wave * 4096;     // 8KB per wave
#pragma unroll
    for (int i = 0; i < AI; ++i) {
      float rr[4][4], hh[4][4];  // [r][ss]
#pragma unroll
      for (int r = 0; r < 4; ++r) {
        const int row = by * 256 + wm * 64 + i * 16 + (lane >> 4) * 4 + r;
        const float4 rv = *(const float4*)(scal + (long)row * 8);
        const float4 hv = *(const float4*)(scal + (long)row * 8 + 4);
        rr[r][0] = rv.x; rr[r][1] = rv.y; rr[r][2] = rv.z; rr[r][3] = rv.w;
        hh[r][0] = hv.x; hh[r][1] = hv.y; hh[r][2] = hv.z; hh[r][3] = hv.w;
      }
#pragma unroll
      for (int jc = 0; jc < 2; ++jc) {
#pragma unroll
        for (int jj = 0; jj < 2; ++jj) {
          const int j = jc * 2 + jj;
          const int col = bx * 128 + wn * 64 + j * 16 + (lane & 15);
          const float bcol = bias[col];
#pragma unroll
          for (int r = 0; r < 4; ++r) {
            const int row = by * 256 + wm * 64 + i * 16 + (lane >> 4) * 4 + r;
            const float f = acc[i][j][r] + bcol;
            const float xval = X[(long)row * 1024 + col];
            const int lp = ((lane >> 4) * 4 + r) | (((jj << 1) | ((lane & 15) >> 3)) << 4);
#pragma unroll
            for (int ss = 0; ss < 4; ++ss)
              ep[ss * 512 + lp * 8 + (lane & 7)] = f2bf(rr[r][ss] * xval + hh[r][ss] * f);
          }
        }
        const long row16 = by * 16 + wm * 4 + i;
        const long col32 = bx * 4 + wn * 2 + jc;
#pragma unroll
        for (int ss = 0; ss < 4; ++ss)
          *(uint4*)(dst + (row16 * 128 + (long)ss * 32 + col32) * 512 + lane * 8) =
              *(const uint4*)(ep + ss * 512 + lane * 8);
      }
    }
  } else {
    float* dst = (float*)dstv;
    float* ep32 = (float*)(l0 + wave * 4096);  // 8KB per wave = 32 rows x 64 cols f32
#pragma unroll
    for (int half = 0; half < 2; ++half) {
#pragma unroll
      for (int i2 = 0; i2 < 2; ++i2) {
        const int i = half * 2 + i2;
#pragma unroll
        for (int j = 0; j < 4; ++j) {
          const int col = bx * 128 + wn * 64 + j * 16 + (lane & 15);
          const float bcol = bias[col];
#pragma unroll
          for (int r = 0; r < 4; ++r) {
            const long row = by * 256 + wm * 64 + i * 16 + (lane >> 4) * 4 + r;
            ep32[(i2 * 16 + (lane >> 4) * 4 + r) * 64 + j * 16 + (lane & 15)] =
                acc[i][j][r] + bcol + X[row * 1024 + col];
          }
        }
      }
#pragma unroll
      for (int q = 0; q < 8; ++q) {
        const int lr = q * 4 + (lane >> 4);  // local row 0..31
        const long row = by * 256 + wm * 64 + half * 32 + lr;
        const long col = bx * 128 + wn * 64 + (lane & 15) * 4;
        *(float4*)(dst + row * 1024 + col) =
            *(const float4*)(ep32 + lr * 64 + (lane & 15) * 4);
      }
    }
  }
}

extern "C" void kernel_launch(void* const* d_in, const int* in_sizes, int n_in,
                              void* d_out, int out_size, void* d_ws, size_t ws_size,
                              hipStream_t stream) {
  (void)in_sizes; (void)n_in; (void)out_size; (void)ws_size;
  const float* x = (const float*)d_in[0];
  const float* rmsw = (const float*)d_in[1];
  const float* Wdyn = (const float*)d_in[2];
  const float* bias_pre = (const float*)d_in[3];
  const float* bias_post = (const float*)d_in[4];
  const float* bias_res = (const float*)d_in[5];
  const float* a_pre = (const float*)d_in[6];
  const float* a_post = (const float*)d_in[7];
  const float* a_res = (const float*)d_in[8];
  const float* W1 = (const float*)d_in[9];
  const float* b1 = (const float*)d_in[10];
  const float* W2 = (const float*)d_in[11];
  const float* b2 = (const float*)d_in[12];
  const float* Wout = (const float*)d_in[13];
  const float* bout = (const float*)d_in[14];
  float* out = (float*)d_out;
  char* ws = (char*)d_ws;

  // ws layout (MiB): [0,8) W1fm | [8,16) W2fm | [16,24) WOfm | [24,25) WT+scal
  //   [25,89)  h (bf16 FM, KCout=128)
  //   [89,153) merged (bf16 FM, KCout=128) -- initially ALIASED by preA (dead after GEMM1)
  constexpr size_t MB = 1048576;
  u16* W1fm = (u16*)(ws);
  u16* W2fm = (u16*)(ws + 8 * MB);
  u16* WOfm = (u16*)(ws + 16 * MB);
  float* WT = (float*)(ws + 24 * MB);
  float* scal = (float*)(ws + 24 * MB + 98304);
  u16* h = (u16*)(ws + 25 * MB);
  u16* merged = (u16*)(ws + 89 * MB);
  u16* preA = (u16*)(ws + 89 * MB);  // aliases merged (safe: preA dead before GEMM2)

  weff_kernel<<<96, 256, 0, stream>>>(rmsw, Wdyn, WT);
  pack_all<<<6144, 256, 0, stream>>>(W1, W2, Wout, W1fm, W2fm, WOfm);
  prep_tokens<<<512, 512, 0, stream>>>(x, WT, bias_pre, bias_post, bias_res,
                                       a_pre, a_post, a_res, preA, scal);
  // GEMM1: h(FM) = gelu(preA @ W1 + b1)   M=8192 N=4096 K=1024
  //   256x128 tiles: 32 x 32 = 1024 blocks, SWZ=1 (4MB L2 tile per XCD-pass)
  gemm_fm2<0, 8, 1, 0><<<1024, 512, 0, stream>>>(preA, W1fm, 32, 128, b1, nullptr, nullptr, h);
  // GEMM2: merged(FM) = r*x + hp*(h @ W2 + b2)   M=8192 N=1024 K=4096
  //   256x128 tiles: 32 x 8 = 256 blocks (GX=8)
  gemm_fm2<1, 8, 0, 3><<<256, 512, 0, stream>>>(h, W2fm, 128, 128, b2, x, scal, merged);
  // GEMM3: out = merged @ Wout + bout + x        M=8192 N=1024 K=4096
  gemm_fm2<2, 8, 0, 3><<<256, 512, 0, stream>>>(merged, WOfm, 128, 0, bout, x, nullptr, out);
}

// Round 6
// 426.012 us; speedup vs baseline: 1.0046x; 1.0046x over previous
//
#include <hip/hip_runtime.h>

typedef unsigned short u16;
typedef __bf16 bf16x8 __attribute__((ext_vector_type(8)));
typedef float f32x4 __attribute__((ext_vector_type(4)));

__device__ __forceinline__ u16 f2bf(float f) {
  unsigned int u = __builtin_bit_cast(unsigned int, f);
  u += 0x7fffu + ((u >> 16) & 1u);
  return (u16)(u >> 16);
}

// async global->LDS, 16B per lane. LDS dest is wave-uniform base + lane*16 (HW).
__device__ __forceinline__ void gload_lds16(const u16* g, u16* l) {
  __builtin_amdgcn_global_load_lds((const __attribute__((address_space(1))) unsigned int*)g,
                                   (__attribute__((address_space(3))) unsigned int*)l,
                                   16, 0, 0);
}

// Branchless gelu with A&S 7.1.26 erf approx (|err|<=1.5e-7 abs, << bf16 rounding).
__device__ __forceinline__ float gelu_erf(float v) {
  const float z = v * 0.70710678118654752f;
  const float az = fabsf(z);
  const float t = __builtin_amdgcn_rcpf(1.0f + 0.3275911f * az);
  const float p = t * (0.254829592f +
                  t * (-0.284496736f +
                  t * (1.421413741f +
                  t * (-1.453152027f + t * 1.061405429f))));
  const float e = __expf(-az * az);
  float er = 1.0f - p * e;
  er = (z < 0.f) ? -er : er;
  return 0.5f * v * (1.0f + er);
}

// ===== Fragment-major (FM) layout for 16x16x32 bf16 MFMA operands =====
// chunk (ri=r>>4, ki=k>>5) is 64 lanes x 16B, contiguous 1KB:
//   lane = (r&15) | (((k>>3)&3)<<4),  byte = (k&7)*2
//   u16 addr(r,k) = ((ri*KC + ki)*512) + lane*8 + (k&7)      [KC = K/32]

// ---------------- WT[j][c] = sum_s rmsw[s*1024+c] * Wdyn[(s*1024+c)*24 + j] ------------
__global__ __launch_bounds__(256) void weff_kernel(const float* __restrict__ rmsw,
                                                   const float* __restrict__ Wdyn,
                                                   float* __restrict__ WT) {
  int idx = blockIdx.x * 256 + threadIdx.x;  // 24576 threads
  int j = idx >> 10, c = idx & 1023;
  float s = 0.f;
#pragma unroll
  for (int st = 0; st < 4; ++st) {
    int r = st * 1024 + c;
    s += rmsw[r] * Wdyn[(long)r * 24 + j];
  }
  WT[idx] = s;
}

// ---------------- pack all 3 weights (K x N fp32) -> FM bf16 of B^T in ONE dispatch ----
__global__ __launch_bounds__(256) void pack_all(const float* __restrict__ W1,
                                                const float* __restrict__ W2,
                                                const float* __restrict__ WO,
                                                u16* __restrict__ F1,
                                                u16* __restrict__ F2,
                                                u16* __restrict__ FO) {
  const int blk = blockIdx.x;
  const int sel = blk >> 11;  // 0,1,2 (2048 blocks each)
  const float* W;
  u16* FMB;
  int lgN, KC;
  if (sel == 0)      { W = W1; FMB = F1; lgN = 12; KC = 32; }
  else if (sel == 1) { W = W2; FMB = F2; lgN = 10; KC = 128; }
  else               { W = WO; FMB = FO; lgN = 10; KC = 128; }
  const long gid = (long)(blk & 2047) * 256 + threadIdx.x;  // N*K/8 threads
  const int N = 1 << lgN;
  const int n = (int)(gid & (N - 1));
  const int k0 = (int)(gid >> lgN) * 8;
  unsigned int p[4];
#pragma unroll
  for (int d = 0; d < 4; ++d) {
    const float lo = W[(long)(k0 + 2 * d) * N + n];
    const float hi = W[(long)(k0 + 2 * d + 1) * N + n];
    p[d] = (unsigned)f2bf(lo) | ((unsigned)f2bf(hi) << 16);
  }
  const long ad = ((long)(n >> 4) * KC + (k0 >> 5)) * 512 +
                  ((n & 15) + (((k0 >> 3) & 3) << 4)) * 8;
  *(uint4*)(FMB + ad) = make_uint4(p[0], p[1], p[2], p[3]);
}

// ---------------- per-token prep v2 (PROVEN in R4; v3's WT-in-LDS regressed 35us:
// 4 distinct cc addresses 128B apart -> same 4 banks -> 4-way ds_read_b128 conflict,
// plus 96KB LDS -> 1 block/CU) ----------------------------------------------------------
__global__ __launch_bounds__(512) void prep_tokens(
    const float* __restrict__ x, const float* __restrict__ WT,
    const float* __restrict__ bias_pre, const float* __restrict__ bias_post,
    const float* __restrict__ bias_res, const float* __restrict__ a_pre,
    const float* __restrict__ a_post, const float* __restrict__ a_res,
    u16* __restrict__ preA, float* __restrict__ scal) {
  const int tid = threadIdx.x;
  const int b = blockIdx.x;          // 512 blocks, 16 tokens each
  const long t0 = (long)b * 16;

  __shared__ float red[32][16][26];  // [cc][tt][j] 53.2KB
  __shared__ float tot2[16][26];
  __shared__ float spre[16];

  // ---- phase 1: partial dots (thread = (tt = tid&15, cc = tid>>4), 32 c's each) ----
  {
    const int tt = tid & 15;
    const int cc = tid >> 4;  // 0..31
    const float* xp = x + (t0 + tt) * 1024 + cc * 32;
    float part[25];
#pragma unroll
    for (int j = 0; j < 25; ++j) part[j] = 0.f;
#pragma unroll
    for (int g = 0; g < 8; ++g) {
      const float4 xv = *(const float4*)(xp + g * 4);
      part[24] += xv.x * xv.x + xv.y * xv.y + xv.z * xv.z + xv.w * xv.w;
#pragma unroll
      for (int j = 0; j < 24; ++j) {
        const float4 wv = *(const float4*)(WT + (long)j * 1024 + cc * 32 + g * 4);
        part[j] += xv.x * wv.x + xv.y * wv.y + xv.z * wv.z + xv.w * wv.w;
      }
    }
#pragma unroll
    for (int j = 0; j < 25; ++j) red[cc][tt][j] = part[j];
  }
  __syncthreads();

  // ---- phase 2a: reduce over cc (thread = (tt = tid>>5, j = tid&31)) ----
  {
    const int tt = tid >> 5;
    const int j = tid & 31;
    if (j < 25) {
      float s = 0.f;
#pragma unroll
      for (int cc = 0; cc < 32; ++cc) s += red[cc][tt][j];
      tot2[tt][j] = s;
    }
  }
  __syncthreads();

  // ---- phase 2b: gates + sinkhorn (tid<256: thread = (tt = tid>>4, m = tid&15)) ----
  if (tid < 256) {
    const int tt = tid >> 4;
    const int m = tid & 15;
    const long t = t0 + tt;
    const float rms = sqrtf(tot2[tt][24] * (1.0f / 1024.0f) + 1e-8f);
    const float rinv = 1.0f / rms;

    if (m == 0) {
      const float ap = a_pre[0];
      float s_pre = 0.f;
#pragma unroll
      for (int i = 0; i < 4; ++i)
        s_pre += 1.f / (1.f + expf(-(ap * tot2[tt][i] * rinv + bias_pre[i])));
      spre[tt] = s_pre;
    }
    if (m < 4) {
      const float apo = a_post[0];
      float hp = 2.f / (1.f + expf(-(apo * tot2[tt][4 + m] * rinv + bias_post[m])));
      scal[t * 8 + 4 + m] = hp;  // H_post
    }
    const float ar = a_res[0];
    float Mv = expf(ar * tot2[tt][8 + m] * rinv + bias_res[m]);
#pragma unroll
    for (int it = 0; it < 20; ++it) {
      float cs = Mv + __shfl_xor(Mv, 4);
      cs += __shfl_xor(cs, 8);
      Mv = Mv / (cs + 1e-8f);  // col normalize (axis=-2)
      float rs = Mv + __shfl_xor(Mv, 1);
      rs += __shfl_xor(rs, 2);
      Mv = Mv / (rs + 1e-8f);  // row normalize (axis=-1)
    }
    float rs = Mv + __shfl_xor(Mv, 1);
    rs += __shfl_xor(rs, 2);
    if ((m & 3) == 0) scal[t * 8 + (m >> 2)] = rs;  // r_i
  }
  __syncthreads();

  // ---- phase 3: preA as complete FM chunks, coalesced uint4 stores ----
  {
    const int w = tid >> 6;
    const int lane = tid & 63;
    const int tl = lane & 15;
    const int co = (lane >> 4) * 8;
    const float sp = spre[tl];
#pragma unroll
    for (int p = 0; p < 4; ++p) {
      const int ki = p * 8 + w;
      const float* xr = x + (t0 + tl) * 1024 + ki * 32 + co;
      const float4 xa = *(const float4*)(xr);
      const float4 xb = *(const float4*)(xr + 4);
      unsigned q0 = (unsigned)f2bf(sp * xa.x) | ((unsigned)f2bf(sp * xa.y) << 16);
      unsigned q1 = (unsigned)f2bf(sp * xa.z) | ((unsigned)f2bf(sp * xa.w) << 16);
      unsigned q2 = (unsigned)f2bf(sp * xb.x) | ((unsigned)f2bf(sp * xb.y) << 16);
      unsigned q3 = (unsigned)f2bf(sp * xb.z) | ((unsigned)f2bf(sp * xb.w) << 16);
      *(uint4*)(preA + ((long)b * 32 + ki) * 512 + lane * 8) = make_uint4(q0, q1, q2, q3);
    }
  }
}

// ======== GEMM1: deep-pipelined 128x128 FM GEMM (tested SC=4 ledger @ R3 geometry) =====
// 256 threads / 4 waves (2x2), wave tile 64x64, CH=16 chunks (A rows 0-7, B rows 8-15),
// SC=4 chunks staged/wave/step, depth-3 pipeline, 4 LDS buffers = 64KB -> 2 blocks/CU
// (cross-block prologue/epilogue overlap -- what R5's 1-block/CU config lost).
// 2048 blocks, 2D XCD swizzle: per XCD-pass 4(by) x 8(bx): A 1MB + B 2MB = 3MB <= L2;
// bx set is pass-invariant per XCD -> B panel stays L2-hot across all 8 passes.
// Ledger: iter kt issues stage kt+3; end-of-iter vmcnt(8) -> stage kt+1 complete,
// {kt+2,kt+3} in flight. Tail vmcnt(4) then vmcnt(0). Never full-drain mid-loop.
__global__ __launch_bounds__(256, 2) void gemm_fm1(const u16* __restrict__ A,
                                                   const u16* __restrict__ B,
                                                   const float* __restrict__ bias,
                                                   u16* __restrict__ dst) {
  const int tid = threadIdx.x;
  const int lane = tid & 63;
  const int wave = tid >> 6;
  const int wm = wave >> 1, wn = wave & 1;
  const int b = blockIdx.x;
  const int c = b & 7, u = b >> 3;       // c = XCD (round-robin dispatch)
  const int p = u >> 5, v = u & 31;      // pass 0..7, intra-XCD-pass 0..31
  const int by = (p * 2 + (c >> 2)) * 4 + (v >> 3);  // 0..63
  const int bx = (c & 3) * 8 + (v & 7);              // 0..31

  __shared__ u16 lds[4][16][512];
  u16* const l0 = (u16*)lds;

  const u16* gb[4];
#pragma unroll
  for (int l = 0; l < 4; ++l) {
    const int t = wave * 4 + l;
    gb[l] = (t < 8) ? (A + ((long)(by * 8 + t) * 32) * 512 + lane * 8)
                    : (B + ((long)(bx * 8 + (t - 8)) * 32) * 512 + lane * 8);
  }

#define STG(kt)                                                              \
  {                                                                          \
    u16* cb_ = l0 + (((kt) & 3) * 16 + wave * 4) * 512;                      \
    const long ko_ = (long)(kt)*512;                                         \
    _Pragma("unroll") for (int l_ = 0; l_ < 4; ++l_)                         \
        gload_lds16(gb[l_] + ko_, cb_ + l_ * 512);                           \
  }

  f32x4 acc[4][4] = {};

  STG(0); STG(1); STG(2);
  asm volatile("s_waitcnt vmcnt(8)" ::: "memory");
  __builtin_amdgcn_s_barrier();

  for (int kt = 0; kt < 32; ++kt) {
    if (kt + 3 < 32) STG(kt + 3);
    const u16* cb = l0 + (kt & 3) * (16 * 512);
    bf16x8 af[4], bf[4];
#pragma unroll
    for (int i = 0; i < 4; ++i)
      af[i] = *(const bf16x8*)(cb + (wm * 4 + i) * 512 + lane * 8);
#pragma unroll
    for (int j = 0; j < 4; ++j)
      bf[j] = *(const bf16x8*)(cb + (8 + wn * 4 + j) * 512 + lane * 8);
    asm volatile("s_waitcnt lgkmcnt(0)" ::: "memory");
    __builtin_amdgcn_sched_barrier(0);
    __builtin_amdgcn_s_setprio(1);
#pragma unroll
    for (int i = 0; i < 4; ++i)
#pragma unroll
      for (int j = 0; j < 4; ++j)
        acc[i][j] = __builtin_amdgcn_mfma_f32_16x16x32_bf16(af[i], bf[j], acc[i][j], 0, 0, 0);
    __builtin_amdgcn_s_setprio(0);
    if (kt + 4 <= 32)      asm volatile("s_waitcnt vmcnt(8)" ::: "memory");
    else if (kt + 3 == 32) asm volatile("s_waitcnt vmcnt(4)" ::: "memory");
    else                   asm volatile("s_waitcnt vmcnt(0)" ::: "memory");
    __builtin_amdgcn_s_barrier();
  }
#undef STG

  // ---- EPI0 epilogue (R3-proven): gelu -> bf16 FM dst, wave-private LDS bounce ----
  u16* ep = l0 + wave * 4096;
#pragma unroll
  for (int i = 0; i < 4; ++i)
#pragma unroll
    for (int j = 0; j < 4; ++j) {
      const int col = bx * 128 + wn * 64 + j * 16 + (lane & 15);
      const float bcol = bias[col];
#pragma unroll
      for (int r = 0; r < 4; ++r) {
        const float g = gelu_erf(acc[i][j][r] + bcol);
        const int lp = ((lane >> 4) * 4 + r) | ((((j & 1) << 1) | ((lane & 15) >> 3)) << 4);
        ep[(i * 2 + (j >> 1)) * 512 + lp * 8 + (lane & 7)] = f2bf(g);
      }
    }
#pragma unroll
  for (int ch = 0; ch < 8; ++ch) {
    const int i = ch >> 1, jc = ch & 1;
    const long row16 = by * 8 + wm * 4 + i;
    const long col32 = bx * 4 + wn * 2 + jc;
    *(uint4*)(dst + (row16 * 128 + col32) * 512 + lane * 8) =
        *(const uint4*)(ep + ch * 512 + lane * 8);
  }
}

// ======== Deep-pipelined FM GEMM (T3+T4 counted-vmcnt + T5 setprio), XCD-swizzled ======
// NT=8 (256x128): 8 waves 4x2, wave tile 64x64 (AI=4), SC=3, depth-3, 96KB LDS.
// Proven config for GEMM2/3 (K=4096) in R4/R5.
template <int EPI, int NT, int SWZ, int LGGX>
__global__ __launch_bounds__(512, 2) void gemm_fm2(const u16* __restrict__ A,
                                                   const u16* __restrict__ B,
                                                   const int KCtot, const int KCout,
                                                   const float* __restrict__ bias,
                                                   const float* __restrict__ X,
                                                   const float* __restrict__ scal,
                                                   void* __restrict__ dstv) {
  constexpr int CH = 16 + NT;     // chunks per K-step (A rows 0..15, B rows 16..CH-1)
  constexpr int SC = CH / 8;      // chunks staged per wave per K-step
  constexpr int AI = (NT == 16) ? 8 : 4;
  const int tid = threadIdx.x;
  const int lane = tid & 63;
  const int wave = tid >> 6;
  const int wm = (NT == 16) ? (wave >> 2) : (wave >> 1);
  const int wn = (NT == 16) ? (wave & 3) : (wave & 1);
  const int b = blockIdx.x;
  int bx, by;
  if constexpr (SWZ == 1) {
    const int c = b & 7, u = b >> 3;
    const int p = u >> 5, v = u & 31;
    by = (p * 2 + (c >> 2)) * 4 + (v >> 3);
    bx = (c & 3) * 8 + (v & 7);
  } else {
    const int c = b & 7, s = b >> 3;
    bx = s & ((1 << LGGX) - 1);
    by = c * 4 + (s >> LGGX);
  }

  __shared__ u16 lds[4][CH][512];
  u16* const l0 = (u16*)lds;

  const u16* gb[4];
#pragma unroll
  for (int l = 0; l < SC; ++l) {
    const int t = wave * SC + l;
    gb[l] = (t < 16) ? (A + ((long)(by * 16 + t) * KCtot) * 512 + lane * 8)
                     : (B + ((long)(bx * NT + (t - 16)) * KCtot) * 512 + lane * 8);
  }

#define STG(kt)                                                              \
  {                                                                          \
    u16* cb_ = l0 + (((kt) & 3) * CH + wave * SC) * 512;                     \
    const long ko_ = (long)(kt)*512;                                         \
    _Pragma("unroll") for (int l_ = 0; l_ < SC; ++l_)                        \
        gload_lds16(gb[l_] + ko_, cb_ + l_ * 512);                           \
  }

  f32x4 acc[AI][4] = {};

  STG(0); STG(1); STG(2);
  if constexpr (SC == 4) asm volatile("s_waitcnt vmcnt(8)" ::: "memory");
  else                   asm volatile("s_waitcnt vmcnt(6)" ::: "memory");
  __builtin_amdgcn_s_barrier();

  for (int kt = 0; kt < KCtot; ++kt) {
    if (kt + 3 < KCtot) STG(kt + 3);
    const u16* cb = l0 + (kt & 3) * (CH * 512);
    bf16x8 af[AI], bf[4];
#pragma unroll
    for (int i = 0; i < AI; ++i)
      af[i] = *(const bf16x8*)(cb + (wm * AI + i) * 512 + lane * 8);
#pragma unroll
    for (int j = 0; j < 4; ++j)
      bf[j] = *(const bf16x8*)(cb + (16 + wn * 4 + j) * 512 + lane * 8);
    asm volatile("s_waitcnt lgkmcnt(0)" ::: "memory");
    __builtin_amdgcn_sched_barrier(0);
    __builtin_amdgcn_s_setprio(1);
#pragma unroll
    for (int i = 0; i < AI; ++i)
#pragma unroll
      for (int j = 0; j < 4; ++j)
        acc[i][j] = __builtin_amdgcn_mfma_f32_16x16x32_bf16(af[i], bf[j], acc[i][j], 0, 0, 0);
    __builtin_amdgcn_s_setprio(0);
    if (kt + 4 <= KCtot) {
      if constexpr (SC == 4) asm volatile("s_waitcnt vmcnt(8)" ::: "memory");
      else                   asm volatile("s_waitcnt vmcnt(6)" ::: "memory");
    } else if (kt + 3 == KCtot) {
      if constexpr (SC == 4) asm volatile("s_waitcnt vmcnt(4)" ::: "memory");
      else                   asm volatile("s_waitcnt vmcnt(3)" ::: "memory");
    } else {
      asm volatile("s_waitcnt vmcnt(0)" ::: "memory");
    }
    __builtin_amdgcn_s_barrier();
  }
#undef STG

  // ---- Epilogue. C/D layout: col = lane&15, row = (lane>>4)*4 + reg [m89/m91] ----
  if constexpr (EPI == 1) {
    u16* dst = (u16*)dstv;          // merged FM, 128 chunks/rowgroup (k = ss*1024+col)
    u16* ep = l0 + wave * 4096;     // 8KB per wave
#pragma unroll
    for (int i = 0; i < AI; ++i) {
      float rr[4][4], hh[4][4];  // [r][ss]
#pragma unroll
      for (int r = 0; r < 4; ++r) {
        const int row = by * 256 + wm * 64 + i * 16 + (lane >> 4) * 4 + r;
        const float4 rv = *(const float4*)(scal + (long)row * 8);
        const float4 hv = *(const float4*)(scal + (long)row * 8 + 4);
        rr[r][0] = rv.x; rr[r][1] = rv.y; rr[r][2] = rv.z; rr[r][3] = rv.w;
        hh[r][0] = hv.x; hh[r][1] = hv.y; hh[r][2] = hv.z; hh[r][3] = hv.w;
      }
#pragma unroll
      for (int jc = 0; jc < 2; ++jc) {
#pragma unroll
        for (int jj = 0; jj < 2; ++jj) {
          const int j = jc * 2 + jj;
          const int col = bx * 128 + wn * 64 + j * 16 + (lane & 15);
          const float bcol = bias[col];
#pragma unroll
          for (int r = 0; r < 4; ++r) {
            const int row = by * 256 + wm * 64 + i * 16 + (lane >> 4) * 4 + r;
            const float f = acc[i][j][r] + bcol;
            const float xval = X[(long)row * 1024 + col];
            const int lp = ((lane >> 4) * 4 + r) | (((jj << 1) | ((lane & 15) >> 3)) << 4);
#pragma unroll
            for (int ss = 0; ss < 4; ++ss)
              ep[ss * 512 + lp * 8 + (lane & 7)] = f2bf(rr[r][ss] * xval + hh[r][ss] * f);
          }
        }
        const long row16 = by * 16 + wm * 4 + i;
        const long col32 = bx * 4 + wn * 2 + jc;
#pragma unroll
        for (int ss = 0; ss < 4; ++ss)
          *(uint4*)(dst + (row16 * 128 + (long)ss * 32 + col32) * 512 + lane * 8) =
              *(const uint4*)(ep + ss * 512 + lane * 8);
      }
    }
  } else {
    float* dst = (float*)dstv;
    float* ep32 = (float*)(l0 + wave * 4096);  // 8KB per wave = 32 rows x 64 cols f32
#pragma unroll
    for (int half = 0; half < 2; ++half) {
#pragma unroll
      for (int i2 = 0; i2 < 2; ++i2) {
        const int i = half * 2 + i2;
#pragma unroll
        for (int j = 0; j < 4; ++j) {
          const int col = bx * 128 + wn * 64 + j * 16 + (lane & 15);
          const float bcol = bias[col];
#pragma unroll
          for (int r = 0; r < 4; ++r) {
            const long row = by * 256 + wm * 64 + i * 16 + (lane >> 4) * 4 + r;
            ep32[(i2 * 16 + (lane >> 4) * 4 + r) * 64 + j * 16 + (lane & 15)] =
                acc[i][j][r] + bcol + X[row * 1024 + col];
          }
        }
      }
#pragma unroll
      for (int q = 0; q < 8; ++q) {
        const int lr = q * 4 + (lane >> 4);  // local row 0..31
        const long row = by * 256 + wm * 64 + half * 32 + lr;
        const long col = bx * 128 + wn * 64 + (lane & 15) * 4;
        *(float4*)(dst + row * 1024 + col) =
            *(const float4*)(ep32 + lr * 64 + (lane & 15) * 4);
      }
    }
  }
}

extern "C" void kernel_launch(void* const* d_in, const int* in_sizes, int n_in,
                              void* d_out, int out_size, void* d_ws, size_t ws_size,
                              hipStream_t stream) {
  (void)in_sizes; (void)n_in; (void)out_size; (void)ws_size;
  const float* x = (const float*)d_in[0];
  const float* rmsw = (const float*)d_in[1];
  const float* Wdyn = (const float*)d_in[2];
  const float* bias_pre = (const float*)d_in[3];
  const float* bias_post = (const float*)d_in[4];
  const float* bias_res = (const float*)d_in[5];
  const float* a_pre = (const float*)d_in[6];
  const float* a_post = (const float*)d_in[7];
  const float* a_res = (const float*)d_in[8];
  const float* W1 = (const float*)d_in[9];
  const float* b1 = (const float*)d_in[10];
  const float* W2 = (const float*)d_in[11];
  const float* b2 = (const float*)d_in[12];
  const float* Wout = (const float*)d_in[13];
  const float* bout = (const float*)d_in[14];
  float* out = (float*)d_out;
  char* ws = (char*)d_ws;

  // ws layout (MiB): [0,8) W1fm | [8,16) W2fm | [16,24) WOfm | [24,25) WT+scal
  //   [25,89)  h (bf16 FM, KCout=128)
  //   [89,153) merged (bf16 FM, KCout=128) -- initially ALIASED by preA (dead after GEMM1)
  constexpr size_t MB = 1048576;
  u16* W1fm = (u16*)(ws);
  u16* W2fm = (u16*)(ws + 8 * MB);
  u16* WOfm = (u16*)(ws + 16 * MB);
  float* WT = (float*)(ws + 24 * MB);
  float* scal = (float*)(ws + 24 * MB + 98304);
  u16* h = (u16*)(ws + 25 * MB);
  u16* merged = (u16*)(ws + 89 * MB);
  u16* preA = (u16*)(ws + 89 * MB);  // aliases merged (safe: preA dead before GEMM2)

  weff_kernel<<<96, 256, 0, stream>>>(rmsw, Wdyn, WT);
  pack_all<<<6144, 256, 0, stream>>>(W1, W2, Wout, W1fm, W2fm, WOfm);
  prep_tokens<<<512, 512, 0, stream>>>(x, WT, bias_pre, bias_post, bias_res,
                                       a_pre, a_post, a_res, preA, scal);
  // GEMM1: h(FM) = gelu(preA @ W1 + b1)   M=8192 N=4096 K=1024
  //   128x128 tiles: 64 x 32 = 2048 blocks, deep pipeline, 2 blocks/CU
  gemm_fm1<<<2048, 256, 0, stream>>>(preA, W1fm, b1, h);
  // GEMM2: merged(FM) = r*x + hp*(h @ W2 + b2)   M=8192 N=1024 K=4096
  gemm_fm2<1, 8, 0, 3><<<256, 512, 0, stream>>>(h, W2fm, 128, 128, b2, x, scal, merged);
  // GEMM3: out = merged @ Wout + bout + x        M=8192 N=1024 K=4096
  gemm_fm2<2, 8, 0, 3><<<256, 512, 0, stream>>>(merged, WOfm, 128, 0, bout, x, nullptr, out);
}

// Round 7
// 418.127 us; speedup vs baseline: 1.0235x; 1.0189x over previous
//
#include <hip/hip_runtime.h>

typedef unsigned short u16;
typedef __bf16 bf16x8 __attribute__((ext_vector_type(8)));
typedef float f32x4 __attribute__((ext_vector_type(4)));

__device__ __forceinline__ u16 f2bf(float f) {
  unsigned int u = __builtin_bit_cast(unsigned int, f);
  u += 0x7fffu + ((u >> 16) & 1u);
  return (u16)(u >> 16);
}

// async global->LDS, 16B per lane. LDS dest is wave-uniform base + lane*16 (HW).
__device__ __forceinline__ void gload_lds16(const u16* g, u16* l) {
  __builtin_amdgcn_global_load_lds((const __attribute__((address_space(1))) unsigned int*)g,
                                   (__attribute__((address_space(3))) unsigned int*)l,
                                   16, 0, 0);
}

// Branchless gelu with A&S 7.1.26 erf approx (|err|<=1.5e-7 abs, << bf16 rounding).
__device__ __forceinline__ float gelu_erf(float v) {
  const float z = v * 0.70710678118654752f;
  const float az = fabsf(z);
  const float t = __builtin_amdgcn_rcpf(1.0f + 0.3275911f * az);
  const float p = t * (0.254829592f +
                  t * (-0.284496736f +
                  t * (1.421413741f +
                  t * (-1.453152027f + t * 1.061405429f))));
  const float e = __expf(-az * az);
  float er = 1.0f - p * e;
  er = (z < 0.f) ? -er : er;
  return 0.5f * v * (1.0f + er);
}

// ===== Fragment-major (FM) layout for 16x16x32 bf16 MFMA operands =====
// chunk (ri=r>>4, ki=k>>5) is 64 lanes x 16B, contiguous 1KB:
//   lane = (r&15) | (((k>>3)&3)<<4),  byte = (k&7)*2
//   u16 addr(r,k) = ((ri*KC + ki)*512) + lane*8 + (k&7)      [KC = K/32]

// ------- fused: pack 3 weights -> FM bf16  +  weff (WT[j][c]) in ONE dispatch ----------
__global__ __launch_bounds__(256) void pack_weff(const float* __restrict__ W1,
                                                 const float* __restrict__ W2,
                                                 const float* __restrict__ WO,
                                                 u16* __restrict__ F1,
                                                 u16* __restrict__ F2,
                                                 u16* __restrict__ FO,
                                                 const float* __restrict__ rmsw,
                                                 const float* __restrict__ Wdyn,
                                                 float* __restrict__ WT) {
  const int blk = blockIdx.x;
  if (blk >= 6144) {  // weff tail: 96 blocks
    int idx = (blk - 6144) * 256 + threadIdx.x;  // 24576 threads
    int j = idx >> 10, c = idx & 1023;
    float s = 0.f;
#pragma unroll
    for (int st = 0; st < 4; ++st) {
      int r = st * 1024 + c;
      s += rmsw[r] * Wdyn[(long)r * 24 + j];
    }
    WT[idx] = s;
    return;
  }
  const int sel = blk >> 11;  // 0,1,2 (2048 blocks each)
  const float* W;
  u16* FMB;
  int lgN, KC;
  if (sel == 0)      { W = W1; FMB = F1; lgN = 12; KC = 32; }
  else if (sel == 1) { W = W2; FMB = F2; lgN = 10; KC = 128; }
  else               { W = WO; FMB = FO; lgN = 10; KC = 128; }
  const long gid = (long)(blk & 2047) * 256 + threadIdx.x;  // N*K/8 threads
  const int N = 1 << lgN;
  const int n = (int)(gid & (N - 1));
  const int k0 = (int)(gid >> lgN) * 8;
  unsigned int p[4];
#pragma unroll
  for (int d = 0; d < 4; ++d) {
    const float lo = W[(long)(k0 + 2 * d) * N + n];
    const float hi = W[(long)(k0 + 2 * d + 1) * N + n];
    p[d] = (unsigned)f2bf(lo) | ((unsigned)f2bf(hi) << 16);
  }
  const long ad = ((long)(n >> 4) * KC + (k0 >> 5)) * 512 +
                  ((n & 15) + (((k0 >> 3) & 3) << 4)) * 8;
  *(uint4*)(FMB + ad) = make_uint4(p[0], p[1], p[2], p[3]);
}

// ---------------- per-token prep v4: 32 tokens/block, LDS-transposed x -----------------
// v2 (~80us hidden cost) lost to scatter loads: each wave instr touched 4-16 distinct
// 16B lines of WT and x. v4: x loaded in COALESCED 256-col panels into xs (odd pad ->
// dot-phase reads 2-way-free), WT read as clean per-lane float4 (2 addrs/wave, L2-hot),
// 25 register accumulators per thread. Gates/sinkhorn/preA bodies verbatim from v2.
__global__ __launch_bounds__(256) void prep_tokens(
    const float* __restrict__ x, const float* __restrict__ WT,
    const float* __restrict__ bias_pre, const float* __restrict__ bias_post,
    const float* __restrict__ bias_res, const float* __restrict__ a_pre,
    const float* __restrict__ a_post, const float* __restrict__ a_res,
    u16* __restrict__ preA, float* __restrict__ scal) {
  const int tid = threadIdx.x;
  const int b = blockIdx.x;          // 256 blocks, 32 tokens each
  const long t0 = (long)b * 32;

  __shared__ float xs[32 * 257];     // [tok][c_local], odd pad: read banks = tt -> free
  __shared__ float red[8][32][26];   // [q][tt][j]
  __shared__ float tot2[32][26];
  __shared__ float spre[32];

  const int tt = tid & 31;
  const int q = tid >> 5;            // 0..7: c-owner within panel

  float part[25];
#pragma unroll
  for (int j = 0; j < 25; ++j) part[j] = 0.f;

  for (int panel = 0; panel < 4; ++panel) {
    const int cb = panel * 256;
    // ---- stage x panel (32 tok x 256 c), fully coalesced global reads ----
#pragma unroll
    for (int pass = 0; pass < 8; ++pass) {
      const int idx = pass * 256 + tid;
      const int row = idx >> 6;          // wave-uniform
      const int c4 = (idx & 63) * 4;     // lane*4
      const float4 v = *(const float4*)(x + (t0 + row) * 1024 + cb + c4);
      xs[row * 257 + c4 + 0] = v.x;
      xs[row * 257 + c4 + 1] = v.y;
      xs[row * 257 + c4 + 2] = v.z;
      xs[row * 257 + c4 + 3] = v.w;
    }
    __syncthreads();
    // ---- dots: thread (tt, q) covers c_local in [q*32, q*32+32) ----
#pragma unroll 2
    for (int g = 0; g < 8; ++g) {
      const int cl = q * 32 + g * 4;
      float xv0 = xs[tt * 257 + cl + 0];
      float xv1 = xs[tt * 257 + cl + 1];
      float xv2 = xs[tt * 257 + cl + 2];
      float xv3 = xs[tt * 257 + cl + 3];
      const float* wp = WT + cb + cl;
#pragma unroll
      for (int j = 0; j < 24; ++j) {
        const float4 wv = *(const float4*)(wp + j * 1024);
        part[j] += xv0 * wv.x + xv1 * wv.y + xv2 * wv.z + xv3 * wv.w;
      }
      part[24] += xv0 * xv0 + xv1 * xv1 + xv2 * xv2 + xv3 * xv3;
    }
    __syncthreads();  // WAR: xs reused next panel
  }

#pragma unroll
  for (int j = 0; j < 25; ++j) red[q][tt][j] = part[j];
  __syncthreads();

  // ---- reduce over q (thread = (tt = tid&31, jj = tid>>5), j = jj+8k) ----
  {
    const int jj = tid >> 5;
#pragma unroll
    for (int k = 0; k < 4; ++k) {
      const int j = jj + 8 * k;
      if (j < 25) {
        float s = 0.f;
#pragma unroll
        for (int qq = 0; qq < 8; ++qq) s += red[qq][tt][j];
        tot2[tt][j] = s;
      }
    }
  }
  __syncthreads();

  // ---- gates + sinkhorn (2 iterations of 16-token groups; body verbatim v2) ----
  for (int it = 0; it < 2; ++it) {
    const int tg = it * 16 + (tid >> 4);
    const int m = tid & 15;
    const long t = t0 + tg;
    const float rms = sqrtf(tot2[tg][24] * (1.0f / 1024.0f) + 1e-8f);
    const float rinv = 1.0f / rms;

    if (m == 0) {
      const float ap = a_pre[0];
      float s_pre = 0.f;
#pragma unroll
      for (int i = 0; i < 4; ++i)
        s_pre += 1.f / (1.f + expf(-(ap * tot2[tg][i] * rinv + bias_pre[i])));
      spre[tg] = s_pre;
    }
    if (m < 4) {
      const float apo = a_post[0];
      float hp = 2.f / (1.f + expf(-(apo * tot2[tg][4 + m] * rinv + bias_post[m])));
      scal[t * 8 + 4 + m] = hp;  // H_post
    }
    const float ar = a_res[0];
    float Mv = expf(ar * tot2[tg][8 + m] * rinv + bias_res[m]);
#pragma unroll
    for (int si = 0; si < 20; ++si) {
      float cs = Mv + __shfl_xor(Mv, 4);
      cs += __shfl_xor(cs, 8);
      Mv = Mv / (cs + 1e-8f);  // col normalize (axis=-2)
      float rs = Mv + __shfl_xor(Mv, 1);
      rs += __shfl_xor(rs, 2);
      Mv = Mv / (rs + 1e-8f);  // row normalize (axis=-1)
    }
    float rs = Mv + __shfl_xor(Mv, 1);
    rs += __shfl_xor(rs, 2);
    if ((m & 3) == 0) scal[t * 8 + (m >> 2)] = rs;  // r_i
  }
  __syncthreads();

  // ---- preA as complete FM chunks, coalesced uint4 stores (v2 pattern, 32 tokens) ----
  {
    const int w = tid >> 6;
    const int lane = tid & 63;
    const int rg = w & 1;              // row-group (16 tokens) within block
    const int kh = (w >> 1) * 16;      // ki half
    const int tl = lane & 15;
    const int co = (lane >> 4) * 8;
    const float sp = spre[rg * 16 + tl];
#pragma unroll
    for (int kk = 0; kk < 16; ++kk) {
      const int ki = kh + kk;
      const float* xr = x + (t0 + rg * 16 + tl) * 1024 + ki * 32 + co;
      const float4 xa = *(const float4*)(xr);
      const float4 xb = *(const float4*)(xr + 4);
      unsigned q0 = (unsigned)f2bf(sp * xa.x) | ((unsigned)f2bf(sp * xa.y) << 16);
      unsigned q1 = (unsigned)f2bf(sp * xa.z) | ((unsigned)f2bf(sp * xa.w) << 16);
      unsigned q2 = (unsigned)f2bf(sp * xb.x) | ((unsigned)f2bf(sp * xb.y) << 16);
      unsigned q3 = (unsigned)f2bf(sp * xb.z) | ((unsigned)f2bf(sp * xb.w) << 16);
      *(uint4*)(preA + ((long)(b * 2 + rg) * 32 + ki) * 512 + lane * 8) =
          make_uint4(q0, q1, q2, q3);
    }
  }
}

// ======== GEMM1: deep-pipelined 128x128 FM GEMM (unchanged from R6, 90us) ==============
__global__ __launch_bounds__(256, 2) void gemm_fm1(const u16* __restrict__ A,
                                                   const u16* __restrict__ B,
                                                   const float* __restrict__ bias,
                                                   u16* __restrict__ dst) {
  const int tid = threadIdx.x;
  const int lane = tid & 63;
  const int wave = tid >> 6;
  const int wm = wave >> 1, wn = wave & 1;
  const int b = blockIdx.x;
  const int c = b & 7, u = b >> 3;       // c = XCD (round-robin dispatch)
  const int p = u >> 5, v = u & 31;      // pass 0..7, intra-XCD-pass 0..31
  const int by = (p * 2 + (c >> 2)) * 4 + (v >> 3);  // 0..63
  const int bx = (c & 3) * 8 + (v & 7);              // 0..31

  __shared__ u16 lds[4][16][512];
  u16* const l0 = (u16*)lds;

  const u16* gb[4];
#pragma unroll
  for (int l = 0; l < 4; ++l) {
    const int t = wave * 4 + l;
    gb[l] = (t < 8) ? (A + ((long)(by * 8 + t) * 32) * 512 + lane * 8)
                    : (B + ((long)(bx * 8 + (t - 8)) * 32) * 512 + lane * 8);
  }

#define STG(kt)                                                              \
  {                                                                          \
    u16* cb_ = l0 + (((kt) & 3) * 16 + wave * 4) * 512;                      \
    const long ko_ = (long)(kt)*512;                                         \
    _Pragma("unroll") for (int l_ = 0; l_ < 4; ++l_)                         \
        gload_lds16(gb[l_] + ko_, cb_ + l_ * 512);                           \
  }

  f32x4 acc[4][4] = {};

  STG(0); STG(1); STG(2);
  asm volatile("s_waitcnt vmcnt(8)" ::: "memory");
  __builtin_amdgcn_s_barrier();

  for (int kt = 0; kt < 32; ++kt) {
    if (kt + 3 < 32) STG(kt + 3);
    const u16* cb = l0 + (kt & 3) * (16 * 512);
    bf16x8 af[4], bf[4];
#pragma unroll
    for (int i = 0; i < 4; ++i)
      af[i] = *(const bf16x8*)(cb + (wm * 4 + i) * 512 + lane * 8);
#pragma unroll
    for (int j = 0; j < 4; ++j)
      bf[j] = *(const bf16x8*)(cb + (8 + wn * 4 + j) * 512 + lane * 8);
    asm volatile("s_waitcnt lgkmcnt(0)" ::: "memory");
    __builtin_amdgcn_sched_barrier(0);
    __builtin_amdgcn_s_setprio(1);
#pragma unroll
    for (int i = 0; i < 4; ++i)
#pragma unroll
      for (int j = 0; j < 4; ++j)
        acc[i][j] = __builtin_amdgcn_mfma_f32_16x16x32_bf16(af[i], bf[j], acc[i][j], 0, 0, 0);
    __builtin_amdgcn_s_setprio(0);
    if (kt + 4 <= 32)      asm volatile("s_waitcnt vmcnt(8)" ::: "memory");
    else if (kt + 3 == 32) asm volatile("s_waitcnt vmcnt(4)" ::: "memory");
    else                   asm volatile("s_waitcnt vmcnt(0)" ::: "memory");
    __builtin_amdgcn_s_barrier();
  }
#undef STG

  // ---- EPI0 epilogue: gelu -> bf16 FM dst, wave-private LDS bounce ----
  u16* ep = l0 + wave * 4096;
#pragma unroll
  for (int i = 0; i < 4; ++i)
#pragma unroll
    for (int j = 0; j < 4; ++j) {
      const int col = bx * 128 + wn * 64 + j * 16 + (lane & 15);
      const float bcol = bias[col];
#pragma unroll
      for (int r = 0; r < 4; ++r) {
        const float g = gelu_erf(acc[i][j][r] + bcol);
        const int lp = ((lane >> 4) * 4 + r) | ((((j & 1) << 1) | ((lane & 15) >> 3)) << 4);
        ep[(i * 2 + (j >> 1)) * 512 + lp * 8 + (lane & 7)] = f2bf(g);
      }
    }
#pragma unroll
  for (int ch = 0; ch < 8; ++ch) {
    const int i = ch >> 1, jc = ch & 1;
    const long row16 = by * 8 + wm * 4 + i;
    const long col32 = bx * 4 + wn * 2 + jc;
    *(uint4*)(dst + (row16 * 128 + col32) * 512 + lane * 8) =
        *(const uint4*)(ep + ch * 512 + lane * 8);
  }
}

// ======== Deep-pipelined FM GEMM for GEMM2/3 (unchanged from R5/R6) ====================
template <int EPI, int NT, int SWZ, int LGGX>
__global__ __launch_bounds__(512, 2) void gemm_fm2(const u16* __restrict__ A,
                                                   const u16* __restrict__ B,
                                                   const int KCtot, const int KCout,
                                                   const float* __restrict__ bias,
                                                   const float* __restrict__ X,
                                                   const float* __restrict__ scal,
                                                   void* __restrict__ dstv) {
  constexpr int CH = 16 + NT;
  constexpr int SC = CH / 8;
  constexpr int AI = (NT == 16) ? 8 : 4;
  const int tid = threadIdx.x;
  const int lane = tid & 63;
  const int wave = tid >> 6;
  const int wm = (NT == 16) ? (wave >> 2) : (wave >> 1);
  const int wn = (NT == 16) ? (wave & 3) : (wave & 1);
  const int b = blockIdx.x;
  int bx, by;
  if constexpr (SWZ == 1) {
    const int c = b & 7, u = b >> 3;
    const int p = u >> 5, v = u & 31;
    by = (p * 2 + (c >> 2)) * 4 + (v >> 3);
    bx = (c & 3) * 8 + (v & 7);
  } else {
    const int c = b & 7, s = b >> 3;
    bx = s & ((1 << LGGX) - 1);
    by = c * 4 + (s >> LGGX);
  }

  __shared__ u16 lds[4][CH][512];
  u16* const l0 = (u16*)lds;

  const u16* gb[4];
#pragma unroll
  for (int l = 0; l < SC; ++l) {
    const int t = wave * SC + l;
    gb[l] = (t < 16) ? (A + ((long)(by * 16 + t) * KCtot) * 512 + lane * 8)
                     : (B + ((long)(bx * NT + (t - 16)) * KCtot) * 512 + lane * 8);
  }

#define STG(kt)                                                              \
  {                                                                          \
    u16* cb_ = l0 + (((kt) & 3) * CH + wave * SC) * 512;                     \
    const long ko_ = (long)(kt)*512;                                         \
    _Pragma("unroll") for (int l_ = 0; l_ < SC; ++l_)                        \
        gload_lds16(gb[l_] + ko_, cb_ + l_ * 512);                           \
  }

  f32x4 acc[AI][4] = {};

  STG(0); STG(1); STG(2);
  if constexpr (SC == 4) asm volatile("s_waitcnt vmcnt(8)" ::: "memory");
  else                   asm volatile("s_waitcnt vmcnt(6)" ::: "memory");
  __builtin_amdgcn_s_barrier();

  for (int kt = 0; kt < KCtot; ++kt) {
    if (kt + 3 < KCtot) STG(kt + 3);
    const u16* cb = l0 + (kt & 3) * (CH * 512);
    bf16x8 af[AI], bf[4];
#pragma unroll
    for (int i = 0; i < AI; ++i)
      af[i] = *(const bf16x8*)(cb + (wm * AI + i) * 512 + lane * 8);
#pragma unroll
    for (int j = 0; j < 4; ++j)
      bf[j] = *(const bf16x8*)(cb + (16 + wn * 4 + j) * 512 + lane * 8);
    asm volatile("s_waitcnt lgkmcnt(0)" ::: "memory");
    __builtin_amdgcn_sched_barrier(0);
    __builtin_amdgcn_s_setprio(1);
#pragma unroll
    for (int i = 0; i < AI; ++i)
#pragma unroll
      for (int j = 0; j < 4; ++j)
        acc[i][j] = __builtin_amdgcn_mfma_f32_16x16x32_bf16(af[i], bf[j], acc[i][j], 0, 0, 0);
    __builtin_amdgcn_s_setprio(0);
    if (kt + 4 <= KCtot) {
      if constexpr (SC == 4) asm volatile("s_waitcnt vmcnt(8)" ::: "memory");
      else                   asm volatile("s_waitcnt vmcnt(6)" ::: "memory");
    } else if (kt + 3 == KCtot) {
      if constexpr (SC == 4) asm volatile("s_waitcnt vmcnt(4)" ::: "memory");
      else                   asm volatile("s_waitcnt vmcnt(3)" ::: "memory");
    } else {
      asm volatile("s_waitcnt vmcnt(0)" ::: "memory");
    }
    __builtin_amdgcn_s_barrier();
  }
#undef STG

  // ---- Epilogue. C/D layout: col = lane&15, row = (lane>>4)*4 + reg [m89/m91] ----
  if constexpr (EPI == 1) {
    u16* dst = (u16*)dstv;
    u16* ep = l0 + wave * 4096;
#pragma unroll
    for (int i = 0; i < AI; ++i) {
      float rr[4][4], hh[4][4];
#pragma unroll
      for (int r = 0; r < 4; ++r) {
        const int row = by * 256 + wm * 64 + i * 16 + (lane >> 4) * 4 + r;
        const float4 rv = *(const float4*)(scal + (long)row * 8);
        const float4 hv = *(const float4*)(scal + (long)row * 8 + 4);
        rr[r][0] = rv.x; rr[r][1] = rv.y; rr[r][2] = rv.z; rr[r][3] = rv.w;
        hh[r][0] = hv.x; hh[r][1] = hv.y; hh[r][2] = hv.z; hh[r][3] = hv.w;
      }
#pragma unroll
      for (int jc = 0; jc < 2; ++jc) {
#pragma unroll
        for (int jj = 0; jj < 2; ++jj) {
          const int j = jc * 2 + jj;
          const int col = bx * 128 + wn * 64 + j * 16 + (lane & 15);
          const float bcol = bias[col];
#pragma unroll
          for (int r = 0; r < 4; ++r) {
            const int row = by * 256 + wm * 64 + i * 16 + (lane >> 4) * 4 + r;
            const float f = acc[i][j][r] + bcol;
            const float xval = X[(long)row * 1024 + col];
            const int lp = ((lane >> 4) * 4 + r) | (((jj << 1) | ((lane & 15) >> 3)) << 4);
#pragma unroll
            for (int ss = 0; ss < 4; ++ss)
              ep[ss * 512 + lp * 8 + (lane & 7)] = f2bf(rr[r][ss] * xval + hh[r][ss] * f);
          }
        }
        const long row16 = by * 16 + wm * 4 + i;
        const long col32 = bx * 4 + wn * 2 + jc;
#pragma unroll
        for (int ss = 0; ss < 4; ++ss)
          *(uint4*)(dst + (row16 * 128 + (long)ss * 32 + col32) * 512 + lane * 8) =
              *(const uint4*)(ep + ss * 512 + lane * 8);
      }
    }
  } else {
    float* dst = (float*)dstv;
    float* ep32 = (float*)(l0 + wave * 4096);
#pragma unroll
    for (int half = 0; half < 2; ++half) {
#pragma unroll
      for (int i2 = 0; i2 < 2; ++i2) {
        const int i = half * 2 + i2;
#pragma unroll
        for (int j = 0; j < 4; ++j) {
          const int col = bx * 128 + wn * 64 + j * 16 + (lane & 15);
          const float bcol = bias[col];
#pragma unroll
          for (int r = 0; r < 4; ++r) {
            const long row = by * 256 + wm * 64 + i * 16 + (lane >> 4) * 4 + r;
            ep32[(i2 * 16 + (lane >> 4) * 4 + r) * 64 + j * 16 + (lane & 15)] =
                acc[i][j][r] + bcol + X[row * 1024 + col];
          }
        }
      }
#pragma unroll
      for (int q = 0; q < 8; ++q) {
        const int lr = q * 4 + (lane >> 4);
        const long row = by * 256 + wm * 64 + half * 32 + lr;
        const long col = bx * 128 + wn * 64 + (lane & 15) * 4;
        *(float4*)(dst + row * 1024 + col) =
            *(const float4*)(ep32 + lr * 64 + (lane & 15) * 4);
      }
    }
  }
}

extern "C" void kernel_launch(void* const* d_in, const int* in_sizes, int n_in,
                              void* d_out, int out_size, void* d_ws, size_t ws_size,
                              hipStream_t stream) {
  (void)in_sizes; (void)n_in; (void)out_size; (void)ws_size;
  const float* x = (const float*)d_in[0];
  const float* rmsw = (const float*)d_in[1];
  const float* Wdyn = (const float*)d_in[2];
  const float* bias_pre = (const float*)d_in[3];
  const float* bias_post = (const float*)d_in[4];
  const float* bias_res = (const float*)d_in[5];
  const float* a_pre = (const float*)d_in[6];
  const float* a_post = (const float*)d_in[7];
  const float* a_res = (const float*)d_in[8];
  const float* W1 = (const float*)d_in[9];
  const float* b1 = (const float*)d_in[10];
  const float* W2 = (const float*)d_in[11];
  const float* b2 = (const float*)d_in[12];
  const float* Wout = (const float*)d_in[13];
  const float* bout = (const float*)d_in[14];
  float* out = (float*)d_out;
  char* ws = (char*)d_ws;

  // ws layout (MiB): [0,8) W1fm | [8,16) W2fm | [16,24) WOfm | [24,25) WT+scal
  //   [25,89)  h (bf16 FM, KCout=128)
  //   [89,153) merged (bf16 FM, KCout=128) -- initially ALIASED by preA (dead after GEMM1)
  constexpr size_t MB = 1048576;
  u16* W1fm = (u16*)(ws);
  u16* W2fm = (u16*)(ws + 8 * MB);
  u16* WOfm = (u16*)(ws + 16 * MB);
  float* WT = (float*)(ws + 24 * MB);
  float* scal = (float*)(ws + 24 * MB + 98304);
  u16* h = (u16*)(ws + 25 * MB);
  u16* merged = (u16*)(ws + 89 * MB);
  u16* preA = (u16*)(ws + 89 * MB);  // aliases merged (safe: preA dead before GEMM2)

  pack_weff<<<6240, 256, 0, stream>>>(W1, W2, Wout, W1fm, W2fm, WOfm, rmsw, Wdyn, WT);
  prep_tokens<<<256, 256, 0, stream>>>(x, WT, bias_pre, bias_post, bias_res,
                                       a_pre, a_post, a_res, preA, scal);
  // GEMM1: h(FM) = gelu(preA @ W1 + b1)   M=8192 N=4096 K=1024
  gemm_fm1<<<2048, 256, 0, stream>>>(preA, W1fm, b1, h);
  // GEMM2: merged(FM) = r*x + hp*(h @ W2 + b2)   M=8192 N=1024 K=4096
  gemm_fm2<1, 8, 0, 3><<<256, 512, 0, stream>>>(h, W2fm, 128, 128, b2, x, scal, merged);
  // GEMM3: out = merged @ Wout + bout + x        M=8192 N=1024 K=4096
  gemm_fm2<2, 8, 0, 3><<<256, 512, 0, stream>>>(merged, WOfm, 128, 0, bout, x, nullptr, out);
}